// Round 4
// baseline (256.598 us; speedup 1.0000x reference)
//
#include <hip/hip_runtime.h>
#include <hip/hip_bf16.h>

// FastWeightMemory: B=4, S=4096, H=1024, M=256, chunk=64.
// Pipeline (7 dispatches): W->bf16 convert (+zero ss) -> proj GEMM (epilogue:
// transposed k/v + per-token sumsq atomics) -> chunk outer products (DMA-staged,
// one-sided scale) -> Gram -> merged scan+M-state -> r GEMM -> out GEMM.

typedef __attribute__((ext_vector_type(4))) float  f4;
typedef __attribute__((ext_vector_type(8))) short  bf16x8;

constexpr int   Hdim  = 1024;
constexpr int   Md    = 256;
constexpr float DECAY = 0.99f;
constexpr float MAXN  = 10.0f;

__device__ __forceinline__ unsigned short f2bf(float f) {
  union { float f; unsigned u; } v; v.f = f;
  unsigned r = v.u + 0x7FFFu + ((v.u >> 16) & 1u);
  return (unsigned short)(r >> 16);
}
__device__ __forceinline__ float bf2f(unsigned short h) {
  union { unsigned u; float f; } v; v.u = ((unsigned)h) << 16; return v.f;
}
__device__ __forceinline__ unsigned pk2bf(float a, float b) {
  __hip_bfloat162 h = __float22bfloat162_rn(make_float2(a, b));
  unsigned u; __builtin_memcpy(&u, &h, 4); return u;
}
__device__ __forceinline__ void gll16(const void* gptr, void* lptr) {
  __builtin_amdgcn_global_load_lds(
      (const __attribute__((address_space(1))) unsigned int*)gptr,
      (__attribute__((address_space(3))) unsigned int*)lptr, 16, 0, 0);
}

// ---------------- K0: convert weights to bf16; zero ss accumulators ----------------
__global__ __launch_bounds__(256) void k0_wcvt(
    const float* __restrict__ Wq, const float* __restrict__ Wk,
    const float* __restrict__ Wv, const float* __restrict__ Wo,
    unsigned short* __restrict__ Wb, unsigned short* __restrict__ Wob,
    float* __restrict__ ssk, float* __restrict__ ssv)
{
  int gid = blockIdx.x * 256 + threadIdx.x;   // grid 512 -> 131072 threads
  if (gid < 16384) ssk[gid] = 0.f;
  else if (gid < 32768) ssv[gid - 16384] = 0.f;
  const float* src; unsigned short* dst; int off;
  if (gid < 32768)      { src = Wq; dst = Wb;          off = gid; }
  else if (gid < 65536) { src = Wk; dst = Wb + 262144; off = gid - 32768; }
  else if (gid < 98304) { src = Wv; dst = Wb + 524288; off = gid - 65536; }
  else                  { src = Wo; dst = Wob;         off = gid - 98304; }
  float4 a = ((const float4*)src)[off * 2];
  float4 b = ((const float4*)src)[off * 2 + 1];
  ((uint4*)dst)[off] = make_uint4(pk2bf(a.x, a.y), pk2bf(a.z, a.w),
                                  pk2bf(b.x, b.y), pk2bf(b.z, b.w));
}

// ---------------- K1: projection GEMM (x fp32 @ Wb^T), m97-style ----------------
// q -> chunk-major [pidx][n]; k,v -> transposed [t][m][tok] + sumsq atomics.
__global__ __launch_bounds__(256) void k1_proj(
    const float* __restrict__ x, const unsigned short* __restrict__ Wb,
    unsigned short* __restrict__ qp, unsigned short* __restrict__ kT,
    unsigned short* __restrict__ vT, float* __restrict__ ssk, float* __restrict__ ssv)
{
  __shared__ float          As[128 * 64];   // 32 KB
  __shared__ unsigned short Bs[128 * 64];   // 16 KB
  const int tid = threadIdx.x;
  const int g = blockIdx.x;
  const int xcd = g & 7, wq_ = g >> 3;
  const int ntile = wq_ % 6;
  const int strip = xcd * 16 + wq_ / 6;
  const int row0 = strip * 128;
  const int n0 = ntile * 128;
  const int seg = n0 >> 8;                  // 0:q 1:k 2:v
  const int nw0 = n0 & 255;

  const int lane = tid & 63, wid = tid >> 6;
  const int wm = wid & 1, wn = wid >> 1;
  const int lr = lane & 15, lq = lane >> 4;
  const int arow_l = lane >> 4, aseg_l = lane & 15;
  const int brow_l = lane >> 3, bseg_l = lane & 7;

  f4 acc[4][4];
#pragma unroll
  for (int i = 0; i < 4; ++i)
#pragma unroll
    for (int j = 0; j < 4; ++j) acc[i][j] = f4{0.f, 0.f, 0.f, 0.f};

  for (int kk = 0; kk < Hdim; kk += 64) {
#pragma unroll
    for (int i = 0; i < 8; ++i) {
      int r = wid * 32 + i * 4 + arow_l;
      int s = aseg_l ^ (r & 15);
      gll16(&x[(long)(row0 + r) * Hdim + kk + s * 4], &As[(wid * 32 + i * 4) * 64]);
    }
#pragma unroll
    for (int i = 0; i < 4; ++i) {
      int r = wid * 32 + i * 8 + brow_l;
      int s = bseg_l ^ (r & 7);
      gll16(&Wb[(long)(n0 + r) * Hdim + kk + s * 8], &Bs[(wid * 32 + i * 8) * 64]);
    }
    __syncthreads();
#pragma unroll
    for (int ks = 0; ks < 2; ++ks) {
      bf16x8 af[4], bfr[4];
#pragma unroll
      for (int i = 0; i < 4; ++i) {
        int m = wm * 64 + i * 16 + lr;
        int p0 = (ks * 8 + lq * 2) ^ (m & 15);
        int p1 = p0 ^ 1;
        f4 a0 = *(const f4*)&As[m * 64 + p0 * 4];
        f4 a1 = *(const f4*)&As[m * 64 + p1 * 4];
        union { bf16x8 v; unsigned u[4]; } au;
        au.u[0] = pk2bf(a0[0], a0[1]); au.u[1] = pk2bf(a0[2], a0[3]);
        au.u[2] = pk2bf(a1[0], a1[1]); au.u[3] = pk2bf(a1[2], a1[3]);
        af[i] = au.v;
      }
#pragma unroll
      for (int j = 0; j < 4; ++j) {
        int n = wn * 64 + j * 16 + lr;
        int pb = (ks * 4 + lq) ^ (n & 7);
        bfr[j] = *(const bf16x8*)&Bs[n * 64 + pb * 8];
      }
#pragma unroll
      for (int i = 0; i < 4; ++i)
#pragma unroll
        for (int j = 0; j < 4; ++j)
          acc[i][j] = __builtin_amdgcn_mfma_f32_16x16x32_bf16(af[i], bfr[j], acc[i][j], 0, 0, 0);
    }
    __syncthreads();
  }

  if (seg == 0) {
#pragma unroll
    for (int i = 0; i < 4; ++i)
#pragma unroll
      for (int rr = 0; rr < 4; ++rr) {
        int token = row0 + wm * 64 + i * 16 + lq * 4 + rr;
        int b = token >> 12, s = token & 4095;
        int pidx = (s >> 6) * 256 + b * 64 + (s & 63);
#pragma unroll
        for (int j = 0; j < 4; ++j) {
          int nn = nw0 + wn * 64 + j * 16 + lr;
          qp[(long)pidx * Md + nn] = f2bf(acc[i][j][rr]);
        }
      }
  } else {
    unsigned short* dT = (seg == 1) ? kT : vT;
    float* ss = (seg == 1) ? ssk : ssv;
#pragma unroll
    for (int i = 0; i < 4; ++i)
#pragma unroll
      for (int rr = 0; rr < 4; ++rr) {
        int token = row0 + wm * 64 + i * 16 + lq * 4 + rr;
        int b = token >> 12, s = token & 4095;
        int pidx = (s >> 6) * 256 + b * 64 + (s & 63);
        int tch = pidx >> 8, tin = pidx & 255;
        float sq = 0.f;
#pragma unroll
        for (int j = 0; j < 4; ++j) {
          int nn = nw0 + wn * 64 + j * 16 + lr;
          float vv = acc[i][j][rr];
          dT[(long)tch * 65536 + nn * 256 + tin] = f2bf(vv);
          sq += vv * vv;
        }
        sq += __shfl_xor(sq, 1); sq += __shfl_xor(sq, 2);
        sq += __shfl_xor(sq, 4); sq += __shfl_xor(sq, 8);
        if (lr == 0) atomicAdd(&ss[pidx], sq);
      }
  }
}

// ---------------- K3: O_t = V^T diag(s) K / 256 from transposed layouts, DMA-staged ----------------
// grid (4 i-slices, 64 chunks). A = vT rows (scaled at frag read), B = kT rows.
__global__ __launch_bounds__(256) void k3_outer(
    const unsigned short* __restrict__ kT, const unsigned short* __restrict__ vT,
    const float* __restrict__ ssk, const float* __restrict__ ssv,
    float* __restrict__ O)
{
  __shared__ unsigned short As[64 * 64];    // 8 KB: [i][64 toks]
  __shared__ unsigned short Bs[256 * 64];   // 32 KB: [j][64 toks]
  __shared__ float sLs[256];
  const int tid = threadIdx.x;
  const int t = blockIdx.y;
  const int i0 = blockIdx.x * 64;
  const int lane = tid & 63, wid = tid >> 6;
  const int lr = lane & 15, lq = lane >> 4;
  const int drow = lane >> 3, dseg = lane & 7;

  {
    float a = ssv[t * 256 + tid], b = ssk[t * 256 + tid];
    sLs[tid] = rsqrtf(fmaxf(a, 1e-24f)) * rsqrtf(fmaxf(b, 1e-24f));
  }

  f4 acc[16];
#pragma unroll
  for (int q = 0; q < 16; ++q) acc[q] = f4{0.f, 0.f, 0.f, 0.f};

  for (int tok0 = 0; tok0 < 256; tok0 += 64) {
#pragma unroll
    for (int j = 0; j < 2; ++j) {           // A: 2 instrs/wave (16 rows/wave)
      int r = wid * 16 + j * 8 + drow;
      int s = dseg ^ (r & 7);
      gll16(&vT[(long)t * 65536 + (i0 + r) * 256 + tok0 + s * 8],
            &As[(wid * 16 + j * 8) * 64]);
    }
#pragma unroll
    for (int j = 0; j < 8; ++j) {           // B: 8 instrs/wave (64 rows/wave)
      int r = wid * 64 + j * 8 + drow;
      int s = dseg ^ (r & 7);
      gll16(&kT[(long)t * 65536 + r * 256 + tok0 + s * 8],
            &Bs[(wid * 64 + j * 8) * 64]);
    }
    __syncthreads();
#pragma unroll
    for (int ks = 0; ks < 2; ++ks) {
      int m = wid * 16 + lr;
      int pa = (ks * 4 + lq) ^ (m & 7);
      bf16x8 ar = *(const bf16x8*)&As[m * 64 + pa * 8];
      f4 s0 = *(const f4*)&sLs[tok0 + ks * 32 + lq * 8];
      f4 s1 = *(const f4*)&sLs[tok0 + ks * 32 + lq * 8 + 4];
      union { bf16x8 v; unsigned short e[8]; unsigned u[4]; } au;
      au.v = ar;
      au.u[0] = pk2bf(bf2f(au.e[0]) * s0[0], bf2f(au.e[1]) * s0[1]);
      au.u[1] = pk2bf(bf2f(au.e[2]) * s0[2], bf2f(au.e[3]) * s0[3]);
      au.u[2] = pk2bf(bf2f(au.e[4]) * s1[0], bf2f(au.e[5]) * s1[1]);
      au.u[3] = pk2bf(bf2f(au.e[6]) * s1[2], bf2f(au.e[7]) * s1[3]);
      bf16x8 af = au.v;
#pragma unroll
      for (int jf = 0; jf < 16; ++jf) {
        int n = jf * 16 + lr;
        int pb = (ks * 4 + lq) ^ (n & 7);
        bf16x8 bfr = *(const bf16x8*)&Bs[n * 64 + pb * 8];
        acc[jf] = __builtin_amdgcn_mfma_f32_16x16x32_bf16(af, bfr, acc[jf], 0, 0, 0);
      }
    }
    __syncthreads();
  }
  float* Ot = O + (long)t * 65536;
#pragma unroll
  for (int jf = 0; jf < 16; ++jf)
#pragma unroll
    for (int rr = 0; rr < 4; ++rr) {
      int i = i0 + wid * 16 + lq * 4 + rr;
      Ot[i * 256 + jf * 16 + lr] = acc[jf][rr] * (1.0f / 256.0f);
    }
}

// ---------------- K4: Gram D[i][j] = <O_i, O_j>, 512 K-slices of 128, atomic accumulate ----------------
__global__ __launch_bounds__(256) void k4_gram(const float* __restrict__ O, float* __restrict__ D)
{
  __shared__ unsigned short Tls[64][40];
  const int tid = threadIdx.x;
  const int kbase = blockIdx.x * 128;
  const int lane = tid & 63, wid = tid >> 6;
  const int lr = lane & 15, lq = lane >> 4;
  f4 acc[4];
#pragma unroll
  for (int q = 0; q < 4; ++q) acc[q] = f4{0.f, 0.f, 0.f, 0.f};

  for (int kk = 0; kk < 128; kk += 32) {
    int tk = tid & 7, tr = tid >> 3;
#pragma unroll
    for (int p = 0; p < 2; ++p) {
      int row = tr + 32 * p;
      float4 v = *(const float4*)&O[(long)row * 65536 + kbase + kk + tk * 4];
      *(uint2*)&Tls[row][tk * 4] = make_uint2(pk2bf(v.x, v.y), pk2bf(v.z, v.w));
    }
    __syncthreads();
    bf16x8 af = *(const bf16x8*)&Tls[wid * 16 + lr][lq * 8];
#pragma unroll
    for (int nt = 0; nt < 4; ++nt) {
      bf16x8 bfr = *(const bf16x8*)&Tls[nt * 16 + lr][lq * 8];
      acc[nt] = __builtin_amdgcn_mfma_f32_16x16x32_bf16(af, bfr, acc[nt], 0, 0, 0);
    }
    __syncthreads();
  }
#pragma unroll
  for (int nt = 0; nt < 4; ++nt)
#pragma unroll
    for (int rr = 0; rr < 4; ++rr)
      atomicAdd(&D[(wid * 16 + lq * 4 + rr) * 64 + nt * 16 + lr], acc[nt][rr]);
}

// ---------------- K56: merged scalar scan (wave 0) + pointwise M-state recurrence ----------------
__global__ __launch_bounds__(256) void k56_mstate(const float* __restrict__ O,
    const float* __restrict__ D, unsigned short* __restrict__ Mb)
{
  __shared__ float Dl[64 * 65];
  __shared__ float sarr[64];
  const int tid = threadIdx.x;
  const int col = blockIdx.x * 256 + tid;
  float ov[64];
#pragma unroll
  for (int j = 0; j < 64; ++j) ov[j] = O[(long)j * 65536 + col];
  for (int i = tid; i < 4096; i += 256) Dl[(i >> 6) * 65 + (i & 63)] = D[i];
  __syncthreads();
  if (tid < 64) {
    const int lane = tid;
    float w = 0.f, nm2 = 0.f;
    for (int t = 0; t < 64; ++t) {
      float wt   = __shfl(w, t);
      float Dtt  = Dl[t * 65 + t];
      float nmn2 = DECAY * DECAY * nm2 + 2.f * DECAY * wt + Dtt;
      float nrm  = sqrtf(fmaxf(nmn2, 0.f));
      float s    = MAXN / fmaxf(nrm, MAXN);
      if (lane == 0) sarr[t] = s;
      w   = s * (DECAY * w + Dl[t * 65 + lane]);
      nm2 = s * s * nmn2;
    }
  }
  __syncthreads();
  float m = 0.f;
#pragma unroll
  for (int t = 0; t < 64; ++t) {
    Mb[(long)t * 65536 + col] = f2bf(m);
    m = sarr[t] * (DECAY * m + ov[t]);
  }
}

// ---------------- K7: r_t = Q_t @ M_t^T (bf16), m97-style, grid (2,2,64) ----------------
__global__ __launch_bounds__(256) void k7_rgemm(
    const unsigned short* __restrict__ qp, const unsigned short* __restrict__ Mb,
    unsigned short* __restrict__ rb)
{
  __shared__ unsigned short As[128 * 64];
  __shared__ unsigned short Bs[128 * 64];
  const int tid = threadIdx.x;
  const int t = blockIdx.z;
  const int row0 = t * 256 + blockIdx.y * 128;
  const int n0 = blockIdx.x * 128;
  const unsigned short* Bsrc = Mb + (long)t * 65536;
  const int lane = tid & 63, wid = tid >> 6;
  const int wm = wid & 1, wn = wid >> 1;
  const int lr = lane & 15, lq = lane >> 4;
  const int brow_l = lane >> 3, bseg_l = lane & 7;

  f4 acc[4][4];
#pragma unroll
  for (int i = 0; i < 4; ++i)
#pragma unroll
    for (int j = 0; j < 4; ++j) acc[i][j] = f4{0.f, 0.f, 0.f, 0.f};

  for (int kk = 0; kk < Md; kk += 64) {
#pragma unroll
    for (int i = 0; i < 4; ++i) {
      int r = wid * 32 + i * 8 + brow_l;
      int s = bseg_l ^ (r & 7);
      gll16(&qp[(long)(row0 + r) * Md + kk + s * 8], &As[(wid * 32 + i * 8) * 64]);
      gll16(&Bsrc[(long)(n0 + r) * Md + kk + s * 8], &Bs[(wid * 32 + i * 8) * 64]);
    }
    __syncthreads();
#pragma unroll
    for (int ks = 0; ks < 2; ++ks) {
      bf16x8 af[4], bfr[4];
#pragma unroll
      for (int i = 0; i < 4; ++i) {
        int m = wm * 64 + i * 16 + lr;
        int pa = (ks * 4 + lq) ^ (m & 7);
        af[i] = *(const bf16x8*)&As[m * 64 + pa * 8];
      }
#pragma unroll
      for (int j = 0; j < 4; ++j) {
        int n = wn * 64 + j * 16 + lr;
        int pb = (ks * 4 + lq) ^ (n & 7);
        bfr[j] = *(const bf16x8*)&Bs[n * 64 + pb * 8];
      }
#pragma unroll
      for (int i = 0; i < 4; ++i)
#pragma unroll
        for (int j = 0; j < 4; ++j)
          acc[i][j] = __builtin_amdgcn_mfma_f32_16x16x32_bf16(af[i], bfr[j], acc[i][j], 0, 0, 0);
    }
    __syncthreads();
  }
#pragma unroll
  for (int i = 0; i < 4; ++i)
#pragma unroll
    for (int rr = 0; rr < 4; ++rr) {
      int prow = row0 + wm * 64 + i * 16 + lq * 4 + rr;
#pragma unroll
      for (int j = 0; j < 4; ++j) {
        int n = n0 + wn * 64 + j * 16 + lr;
        rb[(long)prow * Md + n] = f2bf(acc[i][j][rr]);
      }
    }
}

// ---------------- K8: out = r @ Wob^T (fp32, inverse chunk-permute), m97-style ----------------
__global__ __launch_bounds__(256) void k8_out(
    const unsigned short* __restrict__ rb, const unsigned short* __restrict__ Wob,
    float* __restrict__ out)
{
  __shared__ unsigned short As[128 * 64];
  __shared__ unsigned short Bs[128 * 64];
  const int tid = threadIdx.x;
  const int g = blockIdx.x;
  const int xcd = g & 7, wq_ = g >> 3;
  const int ntile = wq_ & 7;
  const int strip = xcd * 16 + (wq_ >> 3);
  const int n0 = ntile * 128;
  const int row0 = strip * 128;
  const int lane = tid & 63, wid = tid >> 6;
  const int wm = wid & 1, wn = wid >> 1;
  const int lr = lane & 15, lq = lane >> 4;
  const int brow_l = lane >> 3, bseg_l = lane & 7;

  f4 acc[4][4];
#pragma unroll
  for (int i = 0; i < 4; ++i)
#pragma unroll
    for (int j = 0; j < 4; ++j) acc[i][j] = f4{0.f, 0.f, 0.f, 0.f};

  for (int kk = 0; kk < Md; kk += 64) {
#pragma unroll
    for (int i = 0; i < 4; ++i) {
      int r = wid * 32 + i * 8 + brow_l;
      int s = bseg_l ^ (r & 7);
      gll16(&rb[(long)(row0 + r) * Md + kk + s * 8], &As[(wid * 32 + i * 8) * 64]);
      gll16(&Wob[(long)(n0 + r) * Md + kk + s * 8], &Bs[(wid * 32 + i * 8) * 64]);
    }
    __syncthreads();
#pragma unroll
    for (int ks = 0; ks < 2; ++ks) {
      bf16x8 af[4], bfr[4];
#pragma unroll
      for (int i = 0; i < 4; ++i) {
        int m = wm * 64 + i * 16 + lr;
        int pa = (ks * 4 + lq) ^ (m & 7);
        af[i] = *(const bf16x8*)&As[m * 64 + pa * 8];
      }
#pragma unroll
      for (int j = 0; j < 4; ++j) {
        int n = wn * 64 + j * 16 + lr;
        int pb = (ks * 4 + lq) ^ (n & 7);
        bfr[j] = *(const bf16x8*)&Bs[n * 64 + pb * 8];
      }
#pragma unroll
      for (int i = 0; i < 4; ++i)
#pragma unroll
        for (int j = 0; j < 4; ++j)
          acc[i][j] = __builtin_amdgcn_mfma_f32_16x16x32_bf16(af[i], bfr[j], acc[i][j], 0, 0, 0);
    }
    __syncthreads();
  }
#pragma unroll
  for (int i = 0; i < 4; ++i)
#pragma unroll
    for (int rr = 0; rr < 4; ++rr) {
      int pidx = row0 + wm * 64 + i * 16 + lq * 4 + rr;
      int t = pidx >> 8, rm = pidx & 255;
      int token = (rm >> 6) * 4096 + t * 64 + (rm & 63);
#pragma unroll
      for (int j = 0; j < 4; ++j) {
        int h = n0 + wn * 64 + j * 16 + lr;
        out[(long)token * Hdim + h] = acc[i][j][rr];
      }
    }
}

extern "C" void kernel_launch(void* const* d_in, const int* in_sizes, int n_in,
                              void* d_out, int out_size, void* d_ws, size_t ws_size,
                              hipStream_t stream) {
  (void)in_sizes; (void)n_in; (void)out_size; (void)ws_size;
  const float* x  = (const float*)d_in[0];
  const float* Wq = (const float*)d_in[1];
  const float* Wk = (const float*)d_in[2];
  const float* Wv = (const float*)d_in[3];
  const float* Wo = (const float*)d_in[4];
  // d_in[5] = M0 (zeros), d_in[6] = chunk_size (=64): baked in.
  float* out = (float*)d_out;
  char* ws = (char*)d_ws;

  // workspace layout (~44.2 MB):
  unsigned short* qp  = (unsigned short*)(ws + 0);          // q chunk-major bf16    8.39 MB
  unsigned short* kT  = (unsigned short*)(ws + 8388608);    // k^T bf16 (later: r)   8.39 MB
  unsigned short* vT  = (unsigned short*)(ws + 16777216);   // v^T bf16 (later: M)   8.39 MB
  float* O    = (float*)(ws + 25165824);                    // O[64][65536] fp32    16.78 MB
  float* D    = (float*)(ws + 41943040);                    // Gram 64x64           16 KB
  float* ssk  = (float*)(ws + 41959424);                    // 16384 fp32           64 KB
  float* ssv  = (float*)(ws + 42024960);                    // 16384 fp32           64 KB
  unsigned short* Wb  = (unsigned short*)(ws + 42090496);   // [768][1024] bf16     1.57 MB
  unsigned short* Wob = (unsigned short*)(ws + 43663360);   // [1024][256] bf16     0.52 MB
  unsigned short* Mb = vT;   // M states reuse v^T region (dead after K3)
  unsigned short* rb = kT;   // r reuses k^T region (dead after K3)

  // D zero: piggyback on k0? D is fully overwritten by k4 atomics only — must zero.
  hipMemsetAsync(D, 0, 64 * 64 * sizeof(float), stream);
  k0_wcvt  <<<512,            256, 0, stream>>>(Wq, Wk, Wv, Wo, Wb, Wob, ssk, ssv);
  k1_proj  <<<768,            256, 0, stream>>>(x, Wb, qp, kT, vT, ssk, ssv);
  k3_outer <<<dim3(4, 64),    256, 0, stream>>>(kT, vT, ssk, ssv, O);
  k4_gram  <<<512,            256, 0, stream>>>(O, D);
  k56_mstate<<<256,           256, 0, stream>>>(O, D, Mb);
  k7_rgemm <<<dim3(2, 2, 64), 256, 0, stream>>>(qp, Mb, rb);
  k8_out   <<<1024,           256, 0, stream>>>(rb, Wob, out);
}

// Round 5
// 230.995 us; speedup vs baseline: 1.1108x; 1.1108x over previous
//
#include <hip/hip_runtime.h>
#include <hip/hip_bf16.h>

// FastWeightMemory: B=4, S=4096, H=1024, M=256, chunk=64.
// Pipeline: memset D -> W cvt -> proj GEMM (coalesced chunk-major epilogue) ->
// k/v transpose+norms -> chunk outer products (DMA) -> Gram -> scan+M-state ->
// r GEMM -> out GEMM.
// Workspace ping-pong: kT/vT live at 25.2-41.9 MB; O aliases dead kb/vb (8.4-25.2 MB);
// rb aliases kT, Mb aliases vT.

typedef __attribute__((ext_vector_type(4))) float  f4;
typedef __attribute__((ext_vector_type(8))) short  bf16x8;

constexpr int   Hdim  = 1024;
constexpr int   Md    = 256;
constexpr float DECAY = 0.99f;
constexpr float MAXN  = 10.0f;

__device__ __forceinline__ unsigned short f2bf(float f) {
  union { float f; unsigned u; } v; v.f = f;
  unsigned r = v.u + 0x7FFFu + ((v.u >> 16) & 1u);
  return (unsigned short)(r >> 16);
}
__device__ __forceinline__ float bf2f(unsigned short h) {
  union { unsigned u; float f; } v; v.u = ((unsigned)h) << 16; return v.f;
}
__device__ __forceinline__ unsigned pk2bf(float a, float b) {
  __hip_bfloat162 h = __float22bfloat162_rn(make_float2(a, b));
  unsigned u; __builtin_memcpy(&u, &h, 4); return u;
}
__device__ __forceinline__ void gll16(const void* gptr, void* lptr) {
  __builtin_amdgcn_global_load_lds(
      (const __attribute__((address_space(1))) unsigned int*)gptr,
      (__attribute__((address_space(3))) unsigned int*)lptr, 16, 0, 0);
}

// ---------------- K0: convert weights to bf16 ----------------
__global__ __launch_bounds__(256) void k0_wcvt(
    const float* __restrict__ Wq, const float* __restrict__ Wk,
    const float* __restrict__ Wv, const float* __restrict__ Wo,
    unsigned short* __restrict__ Wb, unsigned short* __restrict__ Wob)
{
  int gid = blockIdx.x * 256 + threadIdx.x;   // grid 512
  const float* src; unsigned short* dst; int off;
  if (gid < 32768)      { src = Wq; dst = Wb;          off = gid; }
  else if (gid < 65536) { src = Wk; dst = Wb + 262144; off = gid - 32768; }
  else if (gid < 98304) { src = Wv; dst = Wb + 524288; off = gid - 65536; }
  else                  { src = Wo; dst = Wob;         off = gid - 98304; }
  float4 a = ((const float4*)src)[off * 2];
  float4 b = ((const float4*)src)[off * 2 + 1];
  ((uint4*)dst)[off] = make_uint4(pk2bf(a.x, a.y), pk2bf(a.z, a.w),
                                  pk2bf(b.x, b.y), pk2bf(b.z, b.w));
}

// ---------------- K1: projection GEMM (x fp32 @ Wb^T), m97-style, chunk-major bf16 out ----------------
// R3 epilogue restored: coalesced [pidx][n] stores, no atomics.
__global__ __launch_bounds__(256) void k1_proj(
    const float* __restrict__ x, const unsigned short* __restrict__ Wb,
    unsigned short* __restrict__ qp, unsigned short* __restrict__ kb,
    unsigned short* __restrict__ vb)
{
  __shared__ float          As[128 * 64];   // 32 KB
  __shared__ unsigned short Bs[128 * 64];   // 16 KB
  const int tid = threadIdx.x;
  const int g = blockIdx.x;
  const int xcd = g & 7, wq_ = g >> 3;
  const int ntile = wq_ % 6;
  const int strip = xcd * 16 + wq_ / 6;
  const int row0 = strip * 128;
  const int n0 = ntile * 128;
  const int seg = n0 >> 8;                  // 0:q 1:k 2:v
  const int nw0 = n0 & 255;
  unsigned short* dst = (seg == 0) ? qp : ((seg == 1) ? kb : vb);

  const int lane = tid & 63, wid = tid >> 6;
  const int wm = wid & 1, wn = wid >> 1;
  const int lr = lane & 15, lq = lane >> 4;
  const int arow_l = lane >> 4, aseg_l = lane & 15;
  const int brow_l = lane >> 3, bseg_l = lane & 7;

  f4 acc[4][4];
#pragma unroll
  for (int i = 0; i < 4; ++i)
#pragma unroll
    for (int j = 0; j < 4; ++j) acc[i][j] = f4{0.f, 0.f, 0.f, 0.f};

  for (int kk = 0; kk < Hdim; kk += 64) {
#pragma unroll
    for (int i = 0; i < 8; ++i) {
      int r = wid * 32 + i * 4 + arow_l;
      int s = aseg_l ^ (r & 15);
      gll16(&x[(long)(row0 + r) * Hdim + kk + s * 4], &As[(wid * 32 + i * 4) * 64]);
    }
#pragma unroll
    for (int i = 0; i < 4; ++i) {
      int r = wid * 32 + i * 8 + brow_l;
      int s = bseg_l ^ (r & 7);
      gll16(&Wb[(long)(n0 + r) * Hdim + kk + s * 8], &Bs[(wid * 32 + i * 8) * 64]);
    }
    __syncthreads();
#pragma unroll
    for (int ks = 0; ks < 2; ++ks) {
      bf16x8 af[4], bfr[4];
#pragma unroll
      for (int i = 0; i < 4; ++i) {
        int m = wm * 64 + i * 16 + lr;
        int p0 = (ks * 8 + lq * 2) ^ (m & 15);
        int p1 = p0 ^ 1;
        f4 a0 = *(const f4*)&As[m * 64 + p0 * 4];
        f4 a1 = *(const f4*)&As[m * 64 + p1 * 4];
        union { bf16x8 v; unsigned u[4]; } au;
        au.u[0] = pk2bf(a0[0], a0[1]); au.u[1] = pk2bf(a0[2], a0[3]);
        au.u[2] = pk2bf(a1[0], a1[1]); au.u[3] = pk2bf(a1[2], a1[3]);
        af[i] = au.v;
      }
#pragma unroll
      for (int j = 0; j < 4; ++j) {
        int n = wn * 64 + j * 16 + lr;
        int pb = (ks * 4 + lq) ^ (n & 7);
        bfr[j] = *(const bf16x8*)&Bs[n * 64 + pb * 8];
      }
#pragma unroll
      for (int i = 0; i < 4; ++i)
#pragma unroll
        for (int j = 0; j < 4; ++j)
          acc[i][j] = __builtin_amdgcn_mfma_f32_16x16x32_bf16(af[i], bfr[j], acc[i][j], 0, 0, 0);
    }
    __syncthreads();
  }
#pragma unroll
  for (int i = 0; i < 4; ++i)
#pragma unroll
    for (int rr = 0; rr < 4; ++rr) {
      int token = row0 + wm * 64 + i * 16 + lq * 4 + rr;
      int b = token >> 12, s = token & 4095;
      int pidx = (s >> 6) * 256 + b * 64 + (s & 63);   // chunk-major row
#pragma unroll
      for (int j = 0; j < 4; ++j) {
        int nn = nw0 + wn * 64 + j * 16 + lr;
        dst[(long)pidx * Md + nn] = f2bf(acc[i][j][rr]);
      }
    }
}

// ---------------- K2t: per-chunk k/v transpose + per-token sumsq ----------------
// grid 256: (chunk t, array a, tok-half h). LDS tile [m][tok'] per 64-tok sub-phase.
__global__ __launch_bounds__(256) void k2_trans(
    const unsigned short* __restrict__ kb, const unsigned short* __restrict__ vb,
    unsigned short* __restrict__ kT, unsigned short* __restrict__ vT,
    float* __restrict__ ssk, float* __restrict__ ssv)
{
  __shared__ unsigned short Tls[256 * 68];   // 34.8 KB, [m][tok'+pad]
  __shared__ float red[256];
  const int tid = threadIdx.x;
  const int g = blockIdx.x;
  const int t = g >> 2, a = (g >> 1) & 1, h = g & 1;
  const unsigned short* src = a ? vb : kb;
  unsigned short* dst = a ? vT : kT;
  float* ss = a ? ssv : ssk;
  const int w = tid >> 6, l = tid & 63;      // read phase: wave=m-quarter, lane=tok
  const int ms = tid >> 3, seg = tid & 7;    // write phase: 32 m-rows x 8 tok-segs
#pragma unroll
  for (int sub = 0; sub < 2; ++sub) {
    const int tin0 = h * 128 + sub * 64;
    const unsigned short* row = src + ((long)t * 256 + tin0 + l) * 256 + w * 64;
    float sq = 0.f;
#pragma unroll
    for (int i = 0; i < 16; ++i) {
      ushort4 vv = *(const ushort4*)&row[i * 4];
      float f0 = bf2f(vv.x), f1 = bf2f(vv.y), f2 = bf2f(vv.z), f3 = bf2f(vv.w);
      sq += f0 * f0 + f1 * f1 + f2 * f2 + f3 * f3;
      int m = w * 64 + i * 4;
      Tls[(m + 0) * 68 + l] = vv.x;          // conflict-free: lanes = consecutive tok
      Tls[(m + 1) * 68 + l] = vv.y;
      Tls[(m + 2) * 68 + l] = vv.z;
      Tls[(m + 3) * 68 + l] = vv.w;
    }
    red[tid] = sq;
    __syncthreads();
    if (tid < 64)
      ss[t * 256 + tin0 + tid] = red[tid] + red[64 + tid] + red[128 + tid] + red[192 + tid];
    unsigned short* drow = dst + (long)t * 65536 + tin0 + seg * 8;
#pragma unroll
    for (int k = 0; k < 8; ++k) {
      int m = k * 32 + ms;
      uint2 lo = *(const uint2*)&Tls[m * 68 + seg * 8];
      uint2 hi = *(const uint2*)&Tls[m * 68 + seg * 8 + 4];
      *(uint4*)&drow[(long)m * 256] = make_uint4(lo.x, lo.y, hi.x, hi.y);
    }
    __syncthreads();
  }
}

// ---------------- K3: O_t = V^T diag(s) K / 256 from transposed layouts, DMA-staged ----------------
__global__ __launch_bounds__(256) void k3_outer(
    const unsigned short* __restrict__ kT, const unsigned short* __restrict__ vT,
    const float* __restrict__ ssk, const float* __restrict__ ssv,
    float* __restrict__ O)
{
  __shared__ unsigned short As[64 * 64];    // 8 KB
  __shared__ unsigned short Bs[256 * 64];   // 32 KB
  __shared__ float sLs[256];
  const int tid = threadIdx.x;
  const int t = blockIdx.y;
  const int i0 = blockIdx.x * 64;
  const int lane = tid & 63, wid = tid >> 6;
  const int lr = lane & 15, lq = lane >> 4;
  const int drow = lane >> 3, dseg = lane & 7;

  {
    float a = ssv[t * 256 + tid], b = ssk[t * 256 + tid];
    sLs[tid] = rsqrtf(fmaxf(a, 1e-24f)) * rsqrtf(fmaxf(b, 1e-24f));
  }

  f4 acc[16];
#pragma unroll
  for (int q = 0; q < 16; ++q) acc[q] = f4{0.f, 0.f, 0.f, 0.f};

  for (int tok0 = 0; tok0 < 256; tok0 += 64) {
#pragma unroll
    for (int j = 0; j < 2; ++j) {
      int r = wid * 16 + j * 8 + drow;
      int s = dseg ^ (r & 7);
      gll16(&vT[(long)t * 65536 + (i0 + r) * 256 + tok0 + s * 8],
            &As[(wid * 16 + j * 8) * 64]);
    }
#pragma unroll
    for (int j = 0; j < 8; ++j) {
      int r = wid * 64 + j * 8 + drow;
      int s = dseg ^ (r & 7);
      gll16(&kT[(long)t * 65536 + r * 256 + tok0 + s * 8],
            &Bs[(wid * 64 + j * 8) * 64]);
    }
    __syncthreads();
#pragma unroll
    for (int ks = 0; ks < 2; ++ks) {
      int m = wid * 16 + lr;
      int pa = (ks * 4 + lq) ^ (m & 7);
      bf16x8 ar = *(const bf16x8*)&As[m * 64 + pa * 8];
      f4 s0 = *(const f4*)&sLs[tok0 + ks * 32 + lq * 8];
      f4 s1 = *(const f4*)&sLs[tok0 + ks * 32 + lq * 8 + 4];
      union { bf16x8 v; unsigned short e[8]; unsigned u[4]; } au;
      au.v = ar;
      au.u[0] = pk2bf(bf2f(au.e[0]) * s0[0], bf2f(au.e[1]) * s0[1]);
      au.u[1] = pk2bf(bf2f(au.e[2]) * s0[2], bf2f(au.e[3]) * s0[3]);
      au.u[2] = pk2bf(bf2f(au.e[4]) * s1[0], bf2f(au.e[5]) * s1[1]);
      au.u[3] = pk2bf(bf2f(au.e[6]) * s1[2], bf2f(au.e[7]) * s1[3]);
      bf16x8 af = au.v;
#pragma unroll
      for (int jf = 0; jf < 16; ++jf) {
        int n = jf * 16 + lr;
        int pb = (ks * 4 + lq) ^ (n & 7);
        bf16x8 bfr = *(const bf16x8*)&Bs[n * 64 + pb * 8];
        acc[jf] = __builtin_amdgcn_mfma_f32_16x16x32_bf16(af, bfr, acc[jf], 0, 0, 0);
      }
    }
    __syncthreads();
  }
  float* Ot = O + (long)t * 65536;
#pragma unroll
  for (int jf = 0; jf < 16; ++jf)
#pragma unroll
    for (int rr = 0; rr < 4; ++rr) {
      int i = i0 + wid * 16 + lq * 4 + rr;
      Ot[i * 256 + jf * 16 + lr] = acc[jf][rr] * (1.0f / 256.0f);
    }
}

// ---------------- K4: Gram D[i][j] = <O_i, O_j>, 512 K-slices of 128, atomic accumulate ----------------
__global__ __launch_bounds__(256) void k4_gram(const float* __restrict__ O, float* __restrict__ D)
{
  __shared__ unsigned short Tls[64][40];
  const int tid = threadIdx.x;
  const int kbase = blockIdx.x * 128;
  const int lane = tid & 63, wid = tid >> 6;
  const int lr = lane & 15, lq = lane >> 4;
  f4 acc[4];
#pragma unroll
  for (int q = 0; q < 4; ++q) acc[q] = f4{0.f, 0.f, 0.f, 0.f};

  for (int kk = 0; kk < 128; kk += 32) {
    int tk = tid & 7, tr = tid >> 3;
#pragma unroll
    for (int p = 0; p < 2; ++p) {
      int row = tr + 32 * p;
      float4 v = *(const float4*)&O[(long)row * 65536 + kbase + kk + tk * 4];
      *(uint2*)&Tls[row][tk * 4] = make_uint2(pk2bf(v.x, v.y), pk2bf(v.z, v.w));
    }
    __syncthreads();
    bf16x8 af = *(const bf16x8*)&Tls[wid * 16 + lr][lq * 8];
#pragma unroll
    for (int nt = 0; nt < 4; ++nt) {
      bf16x8 bfr = *(const bf16x8*)&Tls[nt * 16 + lr][lq * 8];
      acc[nt] = __builtin_amdgcn_mfma_f32_16x16x32_bf16(af, bfr, acc[nt], 0, 0, 0);
    }
    __syncthreads();
  }
#pragma unroll
  for (int nt = 0; nt < 4; ++nt)
#pragma unroll
    for (int rr = 0; rr < 4; ++rr)
      atomicAdd(&D[(wid * 16 + lq * 4 + rr) * 64 + nt * 16 + lr], acc[nt][rr]);
}

// ---------------- K56: merged scalar scan (wave 0) + pointwise M-state recurrence ----------------
__global__ __launch_bounds__(256) void k56_mstate(const float* __restrict__ O,
    const float* __restrict__ D, unsigned short* __restrict__ Mb)
{
  __shared__ float Dl[64 * 65];
  __shared__ float sarr[64];
  const int tid = threadIdx.x;
  const int col = blockIdx.x * 256 + tid;
  float ov[64];
#pragma unroll
  for (int j = 0; j < 64; ++j) ov[j] = O[(long)j * 65536 + col];
  for (int i = tid; i < 4096; i += 256) Dl[(i >> 6) * 65 + (i & 63)] = D[i];
  __syncthreads();
  if (tid < 64) {
    const int lane = tid;
    float w = 0.f, nm2 = 0.f;
    for (int t = 0; t < 64; ++t) {
      float wt   = __shfl(w, t);
      float Dtt  = Dl[t * 65 + t];
      float nmn2 = DECAY * DECAY * nm2 + 2.f * DECAY * wt + Dtt;
      float nrm  = sqrtf(fmaxf(nmn2, 0.f));
      float s    = MAXN / fmaxf(nrm, MAXN);
      if (lane == 0) sarr[t] = s;
      w   = s * (DECAY * w + Dl[t * 65 + lane]);
      nm2 = s * s * nmn2;
    }
  }
  __syncthreads();
  float m = 0.f;
#pragma unroll
  for (int t = 0; t < 64; ++t) {
    Mb[(long)t * 65536 + col] = f2bf(m);
    m = sarr[t] * (DECAY * m + ov[t]);
  }
}

// ---------------- K7: r_t = Q_t @ M_t^T (bf16), m97-style, grid (2,2,64) ----------------
__global__ __launch_bounds__(256) void k7_rgemm(
    const unsigned short* __restrict__ qp, const unsigned short* __restrict__ Mb,
    unsigned short* __restrict__ rb)
{
  __shared__ unsigned short As[128 * 64];
  __shared__ unsigned short Bs[128 * 64];
  const int tid = threadIdx.x;
  const int t = blockIdx.z;
  const int row0 = t * 256 + blockIdx.y * 128;
  const int n0 = blockIdx.x * 128;
  const unsigned short* Bsrc = Mb + (long)t * 65536;
  const int lane = tid & 63, wid = tid >> 6;
  const int wm = wid & 1, wn = wid >> 1;
  const int lr = lane & 15, lq = lane >> 4;
  const int brow_l = lane >> 3, bseg_l = lane & 7;

  f4 acc[4][4];
#pragma unroll
  for (int i = 0; i < 4; ++i)
#pragma unroll
    for (int j = 0; j < 4; ++j) acc[i][j] = f4{0.f, 0.f, 0.f, 0.f};

  for (int kk = 0; kk < Md; kk += 64) {
#pragma unroll
    for (int i = 0; i < 4; ++i) {
      int r = wid * 32 + i * 8 + brow_l;
      int s = bseg_l ^ (r & 7);
      gll16(&qp[(long)(row0 + r) * Md + kk + s * 8], &As[(wid * 32 + i * 8) * 64]);
      gll16(&Bsrc[(long)(n0 + r) * Md + kk + s * 8], &Bs[(wid * 32 + i * 8) * 64]);
    }
    __syncthreads();
#pragma unroll
    for (int ks = 0; ks < 2; ++ks) {
      bf16x8 af[4], bfr[4];
#pragma unroll
      for (int i = 0; i < 4; ++i) {
        int m = wm * 64 + i * 16 + lr;
        int pa = (ks * 4 + lq) ^ (m & 7);
        af[i] = *(const bf16x8*)&As[m * 64 + pa * 8];
      }
#pragma unroll
      for (int j = 0; j < 4; ++j) {
        int n = wn * 64 + j * 16 + lr;
        int pb = (ks * 4 + lq) ^ (n & 7);
        bfr[j] = *(const bf16x8*)&Bs[n * 64 + pb * 8];
      }
#pragma unroll
      for (int i = 0; i < 4; ++i)
#pragma unroll
        for (int j = 0; j < 4; ++j)
          acc[i][j] = __builtin_amdgcn_mfma_f32_16x16x32_bf16(af[i], bfr[j], acc[i][j], 0, 0, 0);
    }
    __syncthreads();
  }
#pragma unroll
  for (int i = 0; i < 4; ++i)
#pragma unroll
    for (int rr = 0; rr < 4; ++rr) {
      int prow = row0 + wm * 64 + i * 16 + lq * 4 + rr;
#pragma unroll
      for (int j = 0; j < 4; ++j) {
        int n = n0 + wn * 64 + j * 16 + lr;
        rb[(long)prow * Md + n] = f2bf(acc[i][j][rr]);
      }
    }
}

// ---------------- K8: out = r @ Wob^T (fp32, inverse chunk-permute), m97-style ----------------
__global__ __launch_bounds__(256) void k8_out(
    const unsigned short* __restrict__ rb, const unsigned short* __restrict__ Wob,
    float* __restrict__ out)
{
  __shared__ unsigned short As[128 * 64];
  __shared__ unsigned short Bs[128 * 64];
  const int tid = threadIdx.x;
  const int g = blockIdx.x;
  const int xcd = g & 7, wq_ = g >> 3;
  const int ntile = wq_ & 7;
  const int strip = xcd * 16 + (wq_ >> 3);
  const int n0 = ntile * 128;
  const int row0 = strip * 128;
  const int lane = tid & 63, wid = tid >> 6;
  const int wm = wid & 1, wn = wid >> 1;
  const int lr = lane & 15, lq = lane >> 4;
  const int brow_l = lane >> 3, bseg_l = lane & 7;

  f4 acc[4][4];
#pragma unroll
  for (int i = 0; i < 4; ++i)
#pragma unroll
    for (int j = 0; j < 4; ++j) acc[i][j] = f4{0.f, 0.f, 0.f, 0.f};

  for (int kk = 0; kk < Md; kk += 64) {
#pragma unroll
    for (int i = 0; i < 4; ++i) {
      int r = wid * 32 + i * 8 + brow_l;
      int s = bseg_l ^ (r & 7);
      gll16(&rb[(long)(row0 + r) * Md + kk + s * 8], &As[(wid * 32 + i * 8) * 64]);
      gll16(&Wob[(long)(n0 + r) * Md + kk + s * 8], &Bs[(wid * 32 + i * 8) * 64]);
    }
    __syncthreads();
#pragma unroll
    for (int ks = 0; ks < 2; ++ks) {
      bf16x8 af[4], bfr[4];
#pragma unroll
      for (int i = 0; i < 4; ++i) {
        int m = wm * 64 + i * 16 + lr;
        int pa = (ks * 4 + lq) ^ (m & 7);
        af[i] = *(const bf16x8*)&As[m * 64 + pa * 8];
      }
#pragma unroll
      for (int j = 0; j < 4; ++j) {
        int n = wn * 64 + j * 16 + lr;
        int pb = (ks * 4 + lq) ^ (n & 7);
        bfr[j] = *(const bf16x8*)&Bs[n * 64 + pb * 8];
      }
#pragma unroll
      for (int i = 0; i < 4; ++i)
#pragma unroll
        for (int j = 0; j < 4; ++j)
          acc[i][j] = __builtin_amdgcn_mfma_f32_16x16x32_bf16(af[i], bfr[j], acc[i][j], 0, 0, 0);
    }
    __syncthreads();
  }
#pragma unroll
  for (int i = 0; i < 4; ++i)
#pragma unroll
    for (int rr = 0; rr < 4; ++rr) {
      int pidx = row0 + wm * 64 + i * 16 + lq * 4 + rr;
      int t = pidx >> 8, rm = pidx & 255;
      int token = (rm >> 6) * 4096 + t * 64 + (rm & 63);
#pragma unroll
      for (int j = 0; j < 4; ++j) {
        int h = n0 + wn * 64 + j * 16 + lr;
        out[(long)token * Hdim + h] = acc[i][j][rr];
      }
    }
}

extern "C" void kernel_launch(void* const* d_in, const int* in_sizes, int n_in,
                              void* d_out, int out_size, void* d_ws, size_t ws_size,
                              hipStream_t stream) {
  (void)in_sizes; (void)n_in; (void)out_size; (void)ws_size;
  const float* x  = (const float*)d_in[0];
  const float* Wq = (const float*)d_in[1];
  const float* Wk = (const float*)d_in[2];
  const float* Wv = (const float*)d_in[3];
  const float* Wo = (const float*)d_in[4];
  // d_in[5] = M0 (zeros), d_in[6] = chunk_size (=64): baked in.
  float* out = (float*)d_out;
  char* ws = (char*)d_ws;

  // workspace layout (44.2 MB, ping-pong):
  unsigned short* qp  = (unsigned short*)(ws + 0);          // q chunk-major        8.39 MB
  unsigned short* kb  = (unsigned short*)(ws + 8388608);    // k chunk-major        8.39 MB
  unsigned short* vb  = (unsigned short*)(ws + 16777216);   // v chunk-major        8.39 MB
  unsigned short* kT  = (unsigned short*)(ws + 25165824);   // k^T (later: rb)      8.39 MB
  unsigned short* vT  = (unsigned short*)(ws + 33554432);   // v^T (later: Mb)      8.39 MB
  float* O    = (float*)(ws + 8388608);                     // O over dead kb+vb   16.78 MB
  float* D    = (float*)(ws + 41943040);                    // Gram 64x64           16 KB
  float* ssk  = (float*)(ws + 41959424);                    // 16384 fp32           64 KB
  float* ssv  = (float*)(ws + 42024960);                    // 16384 fp32           64 KB
  unsigned short* Wb  = (unsigned short*)(ws + 42090496);   // [768][1024] bf16     1.57 MB
  unsigned short* Wob = (unsigned short*)(ws + 43663360);   // [1024][256] bf16     0.52 MB
  unsigned short* rb = kT;   // r reuses k^T region (dead after K3)
  unsigned short* Mb = vT;   // M states reuse v^T region (dead after K3)

  hipMemsetAsync(D, 0, 64 * 64 * sizeof(float), stream);
  k0_wcvt   <<<512,            256, 0, stream>>>(Wq, Wk, Wv, Wo, Wb, Wob);
  k1_proj   <<<768,            256, 0, stream>>>(x, Wb, qp, kb, vb);
  k2_trans  <<<256,            256, 0, stream>>>(kb, vb, kT, vT, ssk, ssv);
  k3_outer  <<<dim3(4, 64),    256, 0, stream>>>(kT, vT, ssk, ssv, O);
  k4_gram   <<<512,            256, 0, stream>>>(O, D);
  k56_mstate<<<256,            256, 0, stream>>>(O, D, Mb);
  k7_rgemm  <<<dim3(2, 2, 64), 256, 0, stream>>>(qp, Mb, rb);
  k8_out    <<<1024,           256, 0, stream>>>(rb, Wob, out);
}